// Round 1
// baseline (163.852 us; speedup 1.0000x reference)
//
#include <hip/hip_runtime.h>
#include <hip/hip_bf16.h>

typedef unsigned short u16;
typedef __attribute__((ext_vector_type(8))) short bf16x8;
typedef __attribute__((ext_vector_type(4))) float f32x4;

#define S_LEN 2048
#define NHQ   16
#define NHKV  4
#define HD    64
#define QBLK  64
#define KVBLK 64
#define LPAD  72   // padded LDS row length in elements (144B stride -> 2-way bank alias, free)

__device__ __forceinline__ u16 f2bf(float f) {
    union { float f; unsigned u; } cv; cv.f = f;
    unsigned u = cv.u;
    return (u16)((u + 0x7FFFu + ((u >> 16) & 1u)) >> 16);  // RNE
}

__global__ __launch_bounds__(256, 2)
void gqa_fwd_kernel(const float* __restrict__ Qp, const float* __restrict__ Kp,
                    const float* __restrict__ Vp, float* __restrict__ Op)
{
    __shared__ __align__(16) u16 Kl[KVBLK][LPAD];     // K tile, row-major [kv][d]
    __shared__ __align__(16) u16 Vt[HD][LPAD];        // V tile, transposed [dv][kv]
    __shared__ __align__(16) u16 Pl[4][16][LPAD];     // per-wave P tile [q][kv]

    const int tid  = threadIdx.x;
    const int w    = tid >> 6;
    const int lane = tid & 63;
    const int l16  = lane & 15;
    const int quad = lane >> 4;

    // reverse x so heavy (large-nt) blocks dispatch first
    const int q0  = ((int)gridDim.x - 1 - (int)blockIdx.x) * QBLK;
    const int bh  = blockIdx.y;
    const int b   = bh >> 4;      // / NHQ
    const int qh  = bh & 15;      // % NHQ
    const int kvh = qh >> 2;      // GROUP = 4

    const float* Kbase = Kp + (size_t)b * S_LEN * (NHKV * HD) + kvh * HD;
    const float* Vbase = Vp + (size_t)b * S_LEN * (NHKV * HD) + kvh * HD;

    // ---- Q fragments, scale 1/sqrt(64) folded in. A-layout: row=l16, k=quad*8+i ----
    bf16x8 qf[2];
    {
        const int q = q0 + w * 16 + l16;
        const float* qp = Qp + (size_t)(b * S_LEN + q) * (NHQ * HD) + qh * HD;
        #pragma unroll
        for (int kk = 0; kk < 2; ++kk) {
            const float4 x = *(const float4*)(qp + kk * 32 + quad * 8);
            const float4 y = *(const float4*)(qp + kk * 32 + quad * 8 + 4);
            bf16x8 f;
            f[0] = (short)f2bf(x.x * 0.125f); f[1] = (short)f2bf(x.y * 0.125f);
            f[2] = (short)f2bf(x.z * 0.125f); f[3] = (short)f2bf(x.w * 0.125f);
            f[4] = (short)f2bf(y.x * 0.125f); f[5] = (short)f2bf(y.y * 0.125f);
            f[6] = (short)f2bf(y.z * 0.125f); f[7] = (short)f2bf(y.w * 0.125f);
            qf[kk] = f;
        }
    }

    f32x4 oacc[4];
    #pragma unroll
    for (int nb = 0; nb < 4; ++nb) { oacc[nb][0] = 0.f; oacc[nb][1] = 0.f; oacc[nb][2] = 0.f; oacc[nb][3] = 0.f; }
    float m_r[4], l_r[4];
    #pragma unroll
    for (int r = 0; r < 4; ++r) { m_r[r] = -1e30f; l_r[r] = 0.f; }

    const int nt = q0 / KVBLK;   // diagonal tile index

    for (int t = 0; t <= nt; ++t) {
        const int t0 = t * KVBLK;
        if (t) __syncthreads();   // protect Kl/Vt from overwrite while still being read

        // ---- stage K (row-major) and V (transposed) to LDS, f32 -> bf16 ----
        #pragma unroll
        for (int i = 0; i < 4; ++i) {
            const int idx = tid + i * 256;     // 0..1023
            const int row = idx >> 4;          // kv row 0..63
            const int c4  = (idx & 15) * 4;    // d 0..60
            const float4 kx = *(const float4*)(Kbase + (size_t)(t0 + row) * (NHKV * HD) + c4);
            ushort4 kb;
            kb.x = f2bf(kx.x); kb.y = f2bf(kx.y); kb.z = f2bf(kx.z); kb.w = f2bf(kx.w);
            *(ushort4*)(&Kl[row][c4]) = kb;
            const float4 vx = *(const float4*)(Vbase + (size_t)(t0 + row) * (NHKV * HD) + c4);
            Vt[c4 + 0][row] = f2bf(vx.x);
            Vt[c4 + 1][row] = f2bf(vx.y);
            Vt[c4 + 2][row] = f2bf(vx.z);
            Vt[c4 + 3][row] = f2bf(vx.w);
        }
        __syncthreads();

        // ---- S = Q K^T : D-layout, lane holds S[q=quad*4+r][kv=nb*16+l16] ----
        f32x4 s[4];
        #pragma unroll
        for (int nb = 0; nb < 4; ++nb) {
            f32x4 acc = {0.f, 0.f, 0.f, 0.f};
            #pragma unroll
            for (int kk = 0; kk < 2; ++kk) {
                bf16x8 kf = *(const bf16x8*)(&Kl[nb * 16 + l16][kk * 32 + quad * 8]);
                acc = __builtin_amdgcn_mfma_f32_16x16x32_bf16(qf[kk], kf, acc, 0, 0, 0);
            }
            s[nb] = acc;
        }

        // ---- causal mask (only the diagonal tile needs it) ----
        if (t == nt) {
            #pragma unroll
            for (int nb = 0; nb < 4; ++nb)
                #pragma unroll
                for (int r = 0; r < 4; ++r) {
                    const int qg = q0 + w * 16 + quad * 4 + r;
                    const int kg = t0 + nb * 16 + l16;
                    if (kg > qg) s[nb][r] = -1e30f;
                }
        }

        // ---- online softmax update (rows owned per lane: q = quad*4+r) ----
        #pragma unroll
        for (int r = 0; r < 4; ++r) {
            float rmax = fmaxf(fmaxf(s[0][r], s[1][r]), fmaxf(s[2][r], s[3][r]));
            rmax = fmaxf(rmax, __shfl_xor(rmax, 1));
            rmax = fmaxf(rmax, __shfl_xor(rmax, 2));
            rmax = fmaxf(rmax, __shfl_xor(rmax, 4));
            rmax = fmaxf(rmax, __shfl_xor(rmax, 8));
            const float mnew = fmaxf(m_r[r], rmax);
            const float cf   = __expf(m_r[r] - mnew);
            float rsum = 0.f;
            #pragma unroll
            for (int nb = 0; nb < 4; ++nb) {
                const float p = __expf(s[nb][r] - mnew);
                s[nb][r] = p;
                rsum += p;
            }
            rsum += __shfl_xor(rsum, 1);
            rsum += __shfl_xor(rsum, 2);
            rsum += __shfl_xor(rsum, 4);
            rsum += __shfl_xor(rsum, 8);
            l_r[r] = l_r[r] * cf + rsum;
            m_r[r] = mnew;
            #pragma unroll
            for (int nb = 0; nb < 4; ++nb) oacc[nb][r] *= cf;
        }

        // ---- P -> LDS (D-layout write; read back in A-layout) ----
        #pragma unroll
        for (int r = 0; r < 4; ++r)
            #pragma unroll
            for (int nb = 0; nb < 4; ++nb)
                Pl[w][quad * 4 + r][nb * 16 + l16] = f2bf(s[nb][r]);

        // ---- O += P V : A = P (row=l16, k contiguous), B = Vt rows (n=dv) ----
        bf16x8 pf[2];
        #pragma unroll
        for (int kk = 0; kk < 2; ++kk)
            pf[kk] = *(const bf16x8*)(&Pl[w][l16][kk * 32 + quad * 8]);
        #pragma unroll
        for (int nb = 0; nb < 4; ++nb) {
            #pragma unroll
            for (int kk = 0; kk < 2; ++kk) {
                bf16x8 vf = *(const bf16x8*)(&Vt[nb * 16 + l16][kk * 32 + quad * 8]);
                oacc[nb] = __builtin_amdgcn_mfma_f32_16x16x32_bf16(pf[kk], vf, oacc[nb], 0, 0, 0);
            }
        }
    }

    // ---- epilogue: O /= l; out[b][qh][s][dv] (Hkv x GROUP flattens to qh) ----
    float inv[4];
    #pragma unroll
    for (int r = 0; r < 4; ++r) inv[r] = 1.0f / l_r[r];
    float* ob = Op + ((size_t)(b * NHQ + qh) * S_LEN + (q0 + w * 16)) * HD;
    #pragma unroll
    for (int nb = 0; nb < 4; ++nb)
        #pragma unroll
        for (int r = 0; r < 4; ++r)
            ob[(quad * 4 + r) * HD + nb * 16 + l16] = oacc[nb][r] * inv[r];
}

extern "C" void kernel_launch(void* const* d_in, const int* in_sizes, int n_in,
                              void* d_out, int out_size, void* d_ws, size_t ws_size,
                              hipStream_t stream) {
    const float* Q = (const float*)d_in[0];
    const float* K = (const float*)d_in[1];
    const float* V = (const float*)d_in[2];
    // d_in[3] is the causal mask (tril) -- computed analytically, never read.
    float* O = (float*)d_out;
    dim3 grid(S_LEN / QBLK, 2 * NHQ);   // 32 x 32
    dim3 block(256);
    gqa_fwd_kernel<<<grid, block, 0, stream>>>(Q, K, V, O);
}

// Round 2
// 106.602 us; speedup vs baseline: 1.5370x; 1.5370x over previous
//
#include <hip/hip_runtime.h>
#include <hip/hip_bf16.h>

typedef unsigned short u16;
typedef unsigned int u32;
typedef __attribute__((ext_vector_type(8))) short bf16x8;
typedef __attribute__((ext_vector_type(4))) float f32x4;

#define S_LEN 2048
#define NHQ   16
#define NHKV  4
#define HD    64
#define QBLK  64
#define KVBLK 64
#define LPAD  72   // 144B row stride: 9 x 16B slots -> conflict-free b128 reads

__device__ __forceinline__ u16 f2bf(float f) {
    union { float f; u32 u; } cv; cv.f = f;
    u32 u = cv.u;
    return (u16)((u + 0x7FFFu + ((u >> 16) & 1u)) >> 16);  // RNE
}
__device__ __forceinline__ u32 packbf(float lo, float hi) {
    return (u32)f2bf(lo) | ((u32)f2bf(hi) << 16);
}

__global__ __launch_bounds__(256, 2)
void gqa_fwd_kernel(const float* __restrict__ Qp, const float* __restrict__ Kp,
                    const float* __restrict__ Vp, float* __restrict__ Op)
{
    __shared__ __align__(16) u16 Kl[2][KVBLK][LPAD];  // K tile dbuf, [kv][d]
    __shared__ __align__(16) u16 Vt[2][HD][LPAD];     // V tile dbuf, transposed [dv][kv]
    __shared__ __align__(16) u16 Pl[4][16][LPAD];     // per-wave P, [q][kv]

    const int tid  = threadIdx.x;
    const int w    = tid >> 6;
    const int lane = tid & 63;
    const int l16  = lane & 15;
    const int quad = lane >> 4;

    // reverse x so heavy (large-nt) blocks dispatch first
    const int q0  = ((int)gridDim.x - 1 - (int)blockIdx.x) * QBLK;
    const int bh  = blockIdx.y;
    const int b   = bh >> 4;
    const int qh  = bh & 15;
    const int kvh = qh >> 2;

    const float* Kbase = Kp + (size_t)b * S_LEN * (NHKV * HD) + kvh * HD;
    const float* Vbase = Vp + (size_t)b * S_LEN * (NHKV * HD) + kvh * HD;

    // staging maps: K row-major (coalesced 1KB/instr); V column-assigned so the
    // transposed LDS write is 64 contiguous b16 stores (2-way alias = free)
    const int krow = tid >> 4;        // +16*i
    const int kc4  = (tid & 15) * 4;
    const int vrow = tid & 63;
    const int vc0  = (tid >> 6) * 4;  // c4 = vc0 + 16*i

    // ---- Q fragment (B operand of swapped QK^T), scale folded in ----
    bf16x8 qf[2];
    {
        const int q = q0 + w * 16 + l16;
        const float* qp = Qp + (size_t)(b * S_LEN + q) * (NHQ * HD) + qh * HD;
        #pragma unroll
        for (int kk = 0; kk < 2; ++kk) {
            const float4 x = *(const float4*)(qp + kk * 32 + quad * 8);
            const float4 y = *(const float4*)(qp + kk * 32 + quad * 8 + 4);
            bf16x8 f;
            f[0] = (short)f2bf(x.x * 0.125f); f[1] = (short)f2bf(x.y * 0.125f);
            f[2] = (short)f2bf(x.z * 0.125f); f[3] = (short)f2bf(x.w * 0.125f);
            f[4] = (short)f2bf(y.x * 0.125f); f[5] = (short)f2bf(y.y * 0.125f);
            f[6] = (short)f2bf(y.z * 0.125f); f[7] = (short)f2bf(y.w * 0.125f);
            qf[kk] = f;
        }
    }

    f32x4 oacc[4];
    #pragma unroll
    for (int nb = 0; nb < 4; ++nb) { oacc[nb][0]=0.f; oacc[nb][1]=0.f; oacc[nb][2]=0.f; oacc[nb][3]=0.f; }
    float m_s = -1e30f, l_s = 0.f;   // softmax state for row q = l16 (replicated across quads)

    const int nt = q0 / KVBLK;
    int cur = 0;

    // ---- prologue: stage tile 0 into buffer 0 ----
    #pragma unroll
    for (int i = 0; i < 4; ++i) {
        const float4 kx = *(const float4*)(Kbase + (size_t)(krow + 16*i) * (NHKV*HD) + kc4);
        ushort4 kb; kb.x=f2bf(kx.x); kb.y=f2bf(kx.y); kb.z=f2bf(kx.z); kb.w=f2bf(kx.w);
        *(ushort4*)(&Kl[0][krow + 16*i][kc4]) = kb;
        const float4 vx = *(const float4*)(Vbase + (size_t)vrow * (NHKV*HD) + vc0 + 16*i);
        Vt[0][vc0 + 16*i + 0][vrow] = f2bf(vx.x);
        Vt[0][vc0 + 16*i + 1][vrow] = f2bf(vx.y);
        Vt[0][vc0 + 16*i + 2][vrow] = f2bf(vx.z);
        Vt[0][vc0 + 16*i + 3][vrow] = f2bf(vx.w);
    }
    __syncthreads();

    for (int t = 0; t <= nt; ++t) {
        const int t0 = t * KVBLK;
        const bool pf_on = (t < nt);

        // ---- issue prefetch for tile t+1 (consumed after PV) ----
        float4 kpf[4], vpf[4];
        if (pf_on) {
            const int t1 = t0 + KVBLK;
            #pragma unroll
            for (int i = 0; i < 4; ++i) {
                kpf[i] = *(const float4*)(Kbase + (size_t)(t1 + krow + 16*i) * (NHKV*HD) + kc4);
                vpf[i] = *(const float4*)(Vbase + (size_t)(t1 + vrow) * (NHKV*HD) + vc0 + 16*i);
            }
        }

        // ---- swapped QK^T: s[nb][r] = S[kv = t0+nb*16+quad*4+r][q = q0+w*16+l16] ----
        f32x4 s[4];
        #pragma unroll
        for (int nb = 0; nb < 4; ++nb) {
            f32x4 acc = {0.f, 0.f, 0.f, 0.f};
            #pragma unroll
            for (int kk = 0; kk < 2; ++kk) {
                bf16x8 kf = *(const bf16x8*)(&Kl[cur][nb*16 + l16][kk*32 + quad*8]);
                acc = __builtin_amdgcn_mfma_f32_16x16x32_bf16(kf, qf[kk], acc, 0, 0, 0);
            }
            s[nb] = acc;
        }

        // ---- causal mask (diagonal tile only; t0 == q0 there) ----
        if (t == nt) {
            const int qg = w*16 + l16;
            #pragma unroll
            for (int nb = 0; nb < 4; ++nb)
                #pragma unroll
                for (int r = 0; r < 4; ++r)
                    if (nb*16 + quad*4 + r > qg) s[nb][r] = -1e30f;
        }

        // ---- online softmax: 16 local values + 2-shfl cross-quad reduce ----
        float lmax = fmaxf(fmaxf(s[0][0], s[0][1]), fmaxf(s[0][2], s[0][3]));
        #pragma unroll
        for (int nb = 1; nb < 4; ++nb)
            lmax = fmaxf(lmax, fmaxf(fmaxf(s[nb][0], s[nb][1]), fmaxf(s[nb][2], s[nb][3])));
        lmax = fmaxf(lmax, __shfl_xor(lmax, 16));
        lmax = fmaxf(lmax, __shfl_xor(lmax, 32));

        const float mnew = fmaxf(m_s, lmax);
        const float cf   = __expf(m_s - mnew);
        m_s = mnew;

        float lsum = 0.f;
        #pragma unroll
        for (int nb = 0; nb < 4; ++nb)
            #pragma unroll
            for (int r = 0; r < 4; ++r) {
                const float p = __expf(s[nb][r] - mnew);
                s[nb][r] = p;
                lsum += p;
            }
        lsum += __shfl_xor(lsum, 16);
        lsum += __shfl_xor(lsum, 32);
        l_s = l_s * cf + lsum;

        // ---- rescale O (O rows are q = quad*4+r -> broadcast cf from lane quad*4+r) ----
        #pragma unroll
        for (int r = 0; r < 4; ++r) {
            const float cfr = __shfl(cf, quad*4 + r);
            #pragma unroll
            for (int nb = 0; nb < 4; ++nb) oacc[nb][r] *= cfr;
        }

        // ---- P -> Pl (dword writes, ~2-way); read back as A-fragment ----
        #pragma unroll
        for (int nb = 0; nb < 4; ++nb) {
            *(u32*)(&Pl[w][l16][nb*16 + quad*4])     = packbf(s[nb][0], s[nb][1]);
            *(u32*)(&Pl[w][l16][nb*16 + quad*4 + 2]) = packbf(s[nb][2], s[nb][3]);
        }
        bf16x8 pf[2];
        #pragma unroll
        for (int kk = 0; kk < 2; ++kk)
            pf[kk] = *(const bf16x8*)(&Pl[w][l16][kk*32 + quad*8]);

        // ---- O += P V ----
        #pragma unroll
        for (int nb = 0; nb < 4; ++nb) {
            #pragma unroll
            for (int kk = 0; kk < 2; ++kk) {
                bf16x8 vf = *(const bf16x8*)(&Vt[cur][nb*16 + l16][kk*32 + quad*8]);
                oacc[nb] = __builtin_amdgcn_mfma_f32_16x16x32_bf16(pf[kk], vf, oacc[nb], 0, 0, 0);
            }
        }

        // ---- write prefetched tile to the other buffer; single barrier/tile ----
        if (pf_on) {
            #pragma unroll
            for (int i = 0; i < 4; ++i) {
                ushort4 kb; kb.x=f2bf(kpf[i].x); kb.y=f2bf(kpf[i].y); kb.z=f2bf(kpf[i].z); kb.w=f2bf(kpf[i].w);
                *(ushort4*)(&Kl[cur^1][krow + 16*i][kc4]) = kb;
                Vt[cur^1][vc0 + 16*i + 0][vrow] = f2bf(vpf[i].x);
                Vt[cur^1][vc0 + 16*i + 1][vrow] = f2bf(vpf[i].y);
                Vt[cur^1][vc0 + 16*i + 2][vrow] = f2bf(vpf[i].z);
                Vt[cur^1][vc0 + 16*i + 3][vrow] = f2bf(vpf[i].w);
            }
            __syncthreads();
            cur ^= 1;
        }
    }

    // ---- epilogue: O /= l (l broadcast per O-row), coalesced store ----
    float inv[4];
    #pragma unroll
    for (int r = 0; r < 4; ++r) {
        const float lr = __shfl(l_s, quad*4 + r);
        inv[r] = 1.0f / lr;
    }
    float* ob = Op + ((size_t)(b * NHQ + qh) * S_LEN + (q0 + w*16)) * HD;
    #pragma unroll
    for (int nb = 0; nb < 4; ++nb)
        #pragma unroll
        for (int r = 0; r < 4; ++r)
            ob[(quad*4 + r) * HD + nb*16 + l16] = oacc[nb][r] * inv[r];
}

extern "C" void kernel_launch(void* const* d_in, const int* in_sizes, int n_in,
                              void* d_out, int out_size, void* d_ws, size_t ws_size,
                              hipStream_t stream) {
    const float* Q = (const float*)d_in[0];
    const float* K = (const float*)d_in[1];
    const float* V = (const float*)d_in[2];
    // d_in[3] is the causal mask (tril) -- computed analytically, never read.
    float* O = (float*)d_out;
    dim3 grid(S_LEN / QBLK, 2 * NHQ);   // 32 x 32
    dim3 block(256);
    gqa_fwd_kernel<<<grid, block, 0, stream>>>(Q, K, V, O);
}

// Round 3
// 51.438 us; speedup vs baseline: 3.1854x; 2.0724x over previous
//
#include <hip/hip_runtime.h>
#include <hip/hip_bf16.h>

typedef unsigned short u16;
typedef unsigned int u32;
typedef __attribute__((ext_vector_type(8))) short bf16x8;
typedef __attribute__((ext_vector_type(4))) float f32x4;

#define S_LEN 2048
#define NHQ   16
#define NHKV  4
#define HD    64
#define KVBLK 64
#define QBLK  128
#define LPAD  72   // 144B row stride: 9 x 16B slots -> conflict-free b128 reads
// (1/sqrt(64)) * log2(e): QK^T lands in exp2 domain
#define QSCALE 0.18033688011112042f

__device__ __forceinline__ u32 cvt2(float lo, float hi) {
    __hip_bfloat162 h = __float22bfloat162_rn(make_float2(lo, hi));
    union { __hip_bfloat162 h; u32 u; } c; c.h = h; return c.u;   // v_cvt_pk_bf16_f32
}
__device__ __forceinline__ u16 cvt1(float x) {
    __hip_bfloat16 h = __float2bfloat16(x);
    union { __hip_bfloat16 h; u16 u; } c; c.h = h; return c.u;
}

__global__ __launch_bounds__(512, 2)
void gqa_fwd_kernel(const float* __restrict__ Qp, const float* __restrict__ Kp,
                    const float* __restrict__ Vp, float* __restrict__ Op)
{
    __shared__ __align__(16) u16 Kl[2][KVBLK][LPAD];  // K dbuf, [kv][d]
    __shared__ __align__(16) u16 Vt[2][HD][LPAD];     // V dbuf, transposed [dv][kv]
    __shared__ __align__(16) u16 Pl[8][16][LPAD];     // per-wave P

    const int tid  = threadIdx.x;
    const int w    = tid >> 6;
    const int lane = tid & 63;
    const int l16  = lane & 15;
    const int quad = lane >> 4;

    // XCD-pinned decode: bid&7 -> (b,kvh) so each XCD L2 holds ONE K/V stream.
    const int bid = blockIdx.x;
    const int kvh = bid & 3;
    const int b   = (bid >> 2) & 1;
    const int j   = (bid >> 3) & 7;        // pair index 0..7
    const int g   = bid >> 6;              // head-in-group 0..3
    const int qh  = kvh * 4 + g;

    const float* Kbase = Kp + (size_t)b * S_LEN * (NHKV*HD) + kvh*HD;
    const float* Vbase = Vp + (size_t)b * S_LEN * (NHKV*HD) + kvh*HD;
    const float* Qhead = Qp + (size_t)b * S_LEN * (NHQ*HD) + qh*HD;
    float*       Ohead = Op + (size_t)(b*NHQ + qh) * S_LEN * HD;

    // staging maps (512 threads): K row-major coalesced; V transposed,
    // contiguous-row scalar stores (2-way bank alias = free)
    const int krow = tid >> 4;          // 0..31, +32*i
    const int kc4  = (tid & 15) * 4;
    const int vrow = tid & 63;
    const int vc0  = w * 4;             // +32*i

    const int relq = (w << 4) + l16;    // 0..127 within q-tile
    int cur = 0;

    #pragma unroll 1
    for (int pass = 0; pass < 2; ++pass) {
        const int qt = pass ? j : (15 - j);   // paired {15-j, j}: uniform 34 tiles/block
        const int q0 = qt * QBLK;
        const int nt = 2*qt + 1;
        const int tlast = 2*qt + (w >> 2);    // waves 0-3 skip the last tile

        // ---- Q fragment (B operand of swapped QK^T), scale*log2e folded ----
        bf16x8 qf[2];
        {
            const float* qp = Qhead + (size_t)(q0 + relq) * (NHQ*HD);
            #pragma unroll
            for (int kk = 0; kk < 2; ++kk) {
                const float4 x = *(const float4*)(qp + kk*32 + quad*8);
                const float4 y = *(const float4*)(qp + kk*32 + quad*8 + 4);
                u32 tmp[4];
                tmp[0] = cvt2(x.x*QSCALE, x.y*QSCALE);
                tmp[1] = cvt2(x.z*QSCALE, x.w*QSCALE);
                tmp[2] = cvt2(y.x*QSCALE, y.y*QSCALE);
                tmp[3] = cvt2(y.z*QSCALE, y.w*QSCALE);
                qf[kk] = *(bf16x8*)tmp;
            }
        }

        f32x4 oacc[4];
        #pragma unroll
        for (int nb = 0; nb < 4; ++nb) { oacc[nb][0]=0.f; oacc[nb][1]=0.f; oacc[nb][2]=0.f; oacc[nb][3]=0.f; }
        float m_s = -1e30f, l_s = 0.f;

        __syncthreads();   // previous pass finished reading LDS
        // ---- prologue: stage tile 0 into buf cur ----
        #pragma unroll
        for (int i = 0; i < 2; ++i) {
            const float4 kx = *(const float4*)(Kbase + (size_t)(krow + 32*i)*(NHKV*HD) + kc4);
            *(uint2*)(&Kl[cur][krow + 32*i][kc4]) = make_uint2(cvt2(kx.x,kx.y), cvt2(kx.z,kx.w));
            const float4 vx = *(const float4*)(Vbase + (size_t)vrow*(NHKV*HD) + vc0 + 32*i);
            Vt[cur][vc0+32*i+0][vrow] = cvt1(vx.x);
            Vt[cur][vc0+32*i+1][vrow] = cvt1(vx.y);
            Vt[cur][vc0+32*i+2][vrow] = cvt1(vx.z);
            Vt[cur][vc0+32*i+3][vrow] = cvt1(vx.w);
        }
        __syncthreads();

        for (int t = 0; t <= nt; ++t) {
            const bool pf_on = (t < nt);

            // ---- issue prefetch for tile t+1 ----
            float4 kpf[2], vpf[2];
            if (pf_on) {
                const int t1 = (t+1) * KVBLK;
                #pragma unroll
                for (int i = 0; i < 2; ++i) {
                    kpf[i] = *(const float4*)(Kbase + (size_t)(t1 + krow + 32*i)*(NHKV*HD) + kc4);
                    vpf[i] = *(const float4*)(Vbase + (size_t)(t1 + vrow)*(NHKV*HD) + vc0 + 32*i);
                }
            }

            if (t <= tlast) {   // fully-masked tiles: staging only
                // ---- swapped QK^T: lane holds S[kv=nb*16+quad*4+r][q=relq] ----
                f32x4 s[4];
                #pragma unroll
                for (int nb = 0; nb < 4; ++nb) {
                    f32x4 acc = {0.f,0.f,0.f,0.f};
                    #pragma unroll
                    for (int kk = 0; kk < 2; ++kk) {
                        bf16x8 kf = *(const bf16x8*)(&Kl[cur][nb*16 + l16][kk*32 + quad*8]);
                        acc = __builtin_amdgcn_mfma_f32_16x16x32_bf16(kf, qf[kk], acc, 0, 0, 0);
                    }
                    s[nb] = acc;
                }

                if (t == tlast) {   // diagonal sub-tile mask
                    const int rk0 = (t - 2*qt) * 64;
                    #pragma unroll
                    for (int nb = 0; nb < 4; ++nb)
                        #pragma unroll
                        for (int r = 0; r < 4; ++r)
                            if (rk0 + nb*16 + quad*4 + r > relq) s[nb][r] = -1e30f;
                }

                // ---- online softmax (exp2 domain) ----
                float lmax = fmaxf(fmaxf(s[0][0], s[0][1]), fmaxf(s[0][2], s[0][3]));
                #pragma unroll
                for (int nb = 1; nb < 4; ++nb)
                    lmax = fmaxf(lmax, fmaxf(fmaxf(s[nb][0], s[nb][1]), fmaxf(s[nb][2], s[nb][3])));
                lmax = fmaxf(lmax, __shfl_xor(lmax, 16));
                lmax = fmaxf(lmax, __shfl_xor(lmax, 32));

                const float mnew = fmaxf(m_s, lmax);
                const float cf   = __builtin_amdgcn_exp2f(m_s - mnew);
                m_s = mnew;

                float lsum = 0.f;
                #pragma unroll
                for (int nb = 0; nb < 4; ++nb)
                    #pragma unroll
                    for (int r = 0; r < 4; ++r) {
                        const float p = __builtin_amdgcn_exp2f(s[nb][r] - mnew);
                        s[nb][r] = p;
                        lsum += p;
                    }
                lsum += __shfl_xor(lsum, 16);
                lsum += __shfl_xor(lsum, 32);
                l_s = l_s * cf + lsum;

                #pragma unroll
                for (int r = 0; r < 4; ++r) {
                    const float cfr = __shfl(cf, quad*4 + r);
                    #pragma unroll
                    for (int nb = 0; nb < 4; ++nb) oacc[nb][r] *= cfr;
                }

                // ---- P -> Pl (pk-converted dword stores), read back as A-frag ----
                #pragma unroll
                for (int nb = 0; nb < 4; ++nb) {
                    *(u32*)(&Pl[w][l16][nb*16 + quad*4])     = cvt2(s[nb][0], s[nb][1]);
                    *(u32*)(&Pl[w][l16][nb*16 + quad*4 + 2]) = cvt2(s[nb][2], s[nb][3]);
                }
                bf16x8 pfrag[2];
                #pragma unroll
                for (int kk = 0; kk < 2; ++kk)
                    pfrag[kk] = *(const bf16x8*)(&Pl[w][l16][kk*32 + quad*8]);

                // ---- O += P V ----
                #pragma unroll
                for (int nb = 0; nb < 4; ++nb) {
                    #pragma unroll
                    for (int kk = 0; kk < 2; ++kk) {
                        bf16x8 vf = *(const bf16x8*)(&Vt[cur][nb*16 + l16][kk*32 + quad*8]);
                        oacc[nb] = __builtin_amdgcn_mfma_f32_16x16x32_bf16(pfrag[kk], vf, oacc[nb], 0, 0, 0);
                    }
                }
            }

            // ---- write prefetched tile to other buffer; one barrier/tile ----
            if (pf_on) {
                #pragma unroll
                for (int i = 0; i < 2; ++i) {
                    *(uint2*)(&Kl[cur^1][krow + 32*i][kc4]) =
                        make_uint2(cvt2(kpf[i].x,kpf[i].y), cvt2(kpf[i].z,kpf[i].w));
                    Vt[cur^1][vc0+32*i+0][vrow] = cvt1(vpf[i].x);
                    Vt[cur^1][vc0+32*i+1][vrow] = cvt1(vpf[i].y);
                    Vt[cur^1][vc0+32*i+2][vrow] = cvt1(vpf[i].z);
                    Vt[cur^1][vc0+32*i+3][vrow] = cvt1(vpf[i].w);
                }
                __syncthreads();
                cur ^= 1;
            }
        }

        // ---- epilogue for this pass ----
        float inv[4];
        #pragma unroll
        for (int r = 0; r < 4; ++r) {
            const float lr = __shfl(l_s, quad*4 + r);
            inv[r] = 1.0f / lr;
        }
        float* ob = Ohead + (size_t)(q0 + w*16) * HD;
        #pragma unroll
        for (int nb = 0; nb < 4; ++nb)
            #pragma unroll
            for (int r = 0; r < 4; ++r)
                ob[(quad*4 + r)*HD + nb*16 + l16] = oacc[nb][r] * inv[r];
    }
}

extern "C" void kernel_launch(void* const* d_in, const int* in_sizes, int n_in,
                              void* d_out, int out_size, void* d_ws, size_t ws_size,
                              hipStream_t stream) {
    const float* Q = (const float*)d_in[0];
    const float* K = (const float*)d_in[1];
    const float* V = (const float*)d_in[2];
    // d_in[3] (tril mask) computed analytically, never read.
    float* O = (float*)d_out;
    gqa_fwd_kernel<<<dim3(256), dim3(512), 0, stream>>>(Q, K, V, O);
}